// Round 1
// baseline (967.059 us; speedup 1.0000x reference)
//
#include <hip/hip_runtime.h>
#include <math.h>

#define NB     256
#define NFR    384
#define NPTS   543
#define NL     62
#define NFEAT  744
#define EPSF   1e-8f

// _FACE landmark table; for n in [20,62): landmark = n + 481 (501..542 contiguous)
__constant__ int c_face[20] = {33,133,362,263,61,291,199,419,17,84,
                               17,314,405,320,307,375,321,308,324,318};

__device__ __forceinline__ int lm_of(int n) {
    return (n < 20) ? c_face[n] : n + 481;
}

__device__ __forceinline__ float znan(float v) { return (v != v) ? 0.f : v; }

// One block per batch: nose mean (landmark 17, NaN->0.5) and ddof=1 std
// (landmarks NaN->0) for channels x,y. Writes 4 floats/batch to stats.
__global__ __launch_bounds__(256) void stats_kernel(const float* __restrict__ x,
                                                    float* __restrict__ stats) {
    const int b   = blockIdx.x;
    const int tid = threadIdx.x;
    const float* xb = x + (size_t)b * NFR * NPTS * 3;

    float sx = 0.f, sxx = 0.f, sy = 0.f, syy = 0.f;
    for (int i = tid; i < NFR * NL; i += 256) {
        int l = i / NL;
        int n = i - l * NL;
        const float* p = xb + ((size_t)l * NPTS + lm_of(n)) * 3;
        float vx = p[0], vy = p[1];
        vx = (vx != vx) ? 0.f : vx;
        vy = (vy != vy) ? 0.f : vy;
        sx += vx; sxx += vx * vx;
        sy += vy; syy += vy * vy;
    }
    float nx = 0.f, ny = 0.f;
    for (int l = tid; l < NFR; l += 256) {
        const float* p = xb + ((size_t)l * NPTS + 17) * 3;
        float vx = p[0], vy = p[1];
        nx += (vx != vx) ? 0.5f : vx;
        ny += (vy != vy) ? 0.5f : vy;
    }

    // wave(64) shuffle reduction
    #pragma unroll
    for (int off = 32; off > 0; off >>= 1) {
        sx  += __shfl_down(sx,  off);
        sxx += __shfl_down(sxx, off);
        sy  += __shfl_down(sy,  off);
        syy += __shfl_down(syy, off);
        nx  += __shfl_down(nx,  off);
        ny  += __shfl_down(ny,  off);
    }
    __shared__ float red[4][6];
    if ((tid & 63) == 0) {
        int w = tid >> 6;
        red[w][0] = sx;  red[w][1] = sxx;
        red[w][2] = sy;  red[w][3] = syy;
        red[w][4] = nx;  red[w][5] = ny;
    }
    __syncthreads();
    if (tid == 0) {
        float SX = 0, SXX = 0, SY = 0, SYY = 0, NX = 0, NY = 0;
        #pragma unroll
        for (int w = 0; w < 4; ++w) {
            SX += red[w][0]; SXX += red[w][1];
            SY += red[w][2]; SYY += red[w][3];
            NX += red[w][4]; NY += red[w][5];
        }
        const float cnt = (float)(NFR * NL);
        float varx = (SXX - SX * SX / cnt) / (cnt - 1.f);
        float vary = (SYY - SY * SY / cnt) / (cnt - 1.f);
        float stdx = sqrtf(fmaxf(varx, 0.f));
        float stdy = sqrtf(fmaxf(vary, 0.f));
        stats[b * 4 + 0] = NX / (float)NFR;
        stats[b * 4 + 1] = NY / (float)NFR;
        stats[b * 4 + 2] = 1.f / (stdx + EPSF);
        stats[b * 4 + 3] = 1.f / (stdy + EPSF);
    }
}

// One wave per (b, l). Thread n handles landmark n (62 active of 64).
__global__ __launch_bounds__(64) void feat_kernel(const float* __restrict__ x,
                                                  const float* __restrict__ stats,
                                                  float* __restrict__ out) {
    const int l = blockIdx.x;
    const int b = blockIdx.y;
    const int n = threadIdx.x;
    const int nc = (n < NL) ? n : (NL - 1);
    const int lm = lm_of(nc);

    const float mx  = stats[b * 4 + 0];
    const float my  = stats[b * 4 + 1];
    const float ivx = stats[b * 4 + 2];
    const float ivy = stats[b * 4 + 3];

    const float* xb = x + (size_t)b * NFR * NPTS * 3;
    const int l1 = (l + 1 < NFR) ? l + 1 : NFR - 1;
    const int l2 = (l + 2 < NFR) ? l + 2 : NFR - 1;

    const float* p0p = xb + ((size_t)l  * NPTS + lm) * 3;
    const float* p1p = xb + ((size_t)l1 * NPTS + lm) * 3;
    const float* p2p = xb + ((size_t)l2 * NPTS + lm) * 3;

    float p0x = (p0p[0] - mx) * ivx, p0y = (p0p[1] - my) * ivy;
    float p1x = (p1p[0] - mx) * ivx, p1y = (p1p[1] - my) * ivy;
    float p2x = (p2p[0] - mx) * ivx, p2y = (p2p[1] - my) * ivy;

    // neighbor landmark (n+1) at frame l, for relative_motion
    float q0x = __shfl_down(p0x, 1);
    float q0y = __shfl_down(p0y, 1);

    const bool has1 = (l < NFR - 1);
    const bool has2 = (l < NFR - 2);

    float dxx = has1 ? (p1x - p0x) : 0.f;
    float dxy = has1 ? (p1y - p0y) : 0.f;
    float d2x = has2 ? (p2x - p0x) : 0.f;
    float d2y = has2 ? (p2y - p0y) : 0.f;

    float relx = 0.f, rely = 0.f;
    if (has1 && n < NL - 1) {
        relx = p1x - q0x;
        rely = p1y - q0y;
    }

    float tc = 0.f;
    if (has2) {
        float ax = p1x - p0x, ay = p1y - p0y;
        float bx = p2x - p1x, by = p2y - p1y;
        float na = fmaxf(sqrtf(ax * ax + ay * ay), EPSF);
        float nb = fmaxf(sqrtf(bx * bx + by * by), EPSF);
        tc = (ax * bx + ay * by) / (na * nb);
    }

    float mag = sqrtf(dxx * dxx + dxy * dxy);
    float dir = atan2f(dxy, dxx);

    if (n < NL) {
        float* o = out + ((size_t)b * NFR + l) * NFEAT;
        *(float2*)(o + 0   + 2 * n) = make_float2(znan(p0x),  znan(p0y));
        *(float2*)(o + 124 + 2 * n) = make_float2(znan(dxx),  znan(dxy));
        *(float2*)(o + 248 + 2 * n) = make_float2(znan(d2x),  znan(d2y));
        *(float2*)(o + 372 + 2 * n) = make_float2(znan(relx), znan(rely));
        float tz = znan(tc);
        *(float2*)(o + 496 + 2 * n) = make_float2(tz, tz);
        o[620 + n] = znan(mag);
        o[682 + n] = znan(dir);
    }
}

extern "C" void kernel_launch(void* const* d_in, const int* in_sizes, int n_in,
                              void* d_out, int out_size, void* d_ws, size_t ws_size,
                              hipStream_t stream) {
    const float* x   = (const float*)d_in[0];
    float*       out = (float*)d_out;
    float*       st  = (float*)d_ws;  // 256*4 floats

    stats_kernel<<<dim3(NB), dim3(256), 0, stream>>>(x, st);
    feat_kernel<<<dim3(NFR, NB), dim3(64), 0, stream>>>(x, st, out);
}